// Round 7
// baseline (308.039 us; speedup 1.0000x reference)
//
#include <hip/hip_runtime.h>
#include <stdint.h>

// GCN layer: out = prelu(W @ segsum(A_val * h[A_col] -> A_row) + b, act_a)
//            h   = prelu(Wr @ AX + br, g_a)
// R7: fused SpMM+GEMM2 kernel, with T tile ALIASED over eL/eS (R6's +8.7KB
// LDS dropped occupancy 43% and cost 20us of latency hiding); hist_g layout
// transposed to [blk][bucket] so hist write-out / scatter cursor-init are
// contiguous full-line streams (R6 layout: 16 partial 4B writes per line).
// R3 lesson: no fp32 atomics anywhere. R2 lesson: scatter writes must be
// block-contiguous per bucket segment (write-combining).

typedef _Float16 half8 __attribute__((ext_vector_type(8)));
typedef _Float16 half4 __attribute__((ext_vector_type(4)));
typedef _Float16 half2v __attribute__((ext_vector_type(2)));
typedef float floatx4 __attribute__((ext_vector_type(4)));

#define LDK 136        // LDS row stride in halfs: 128 + 8 (keeps 16B row alignment)
#define SHIFT 5        // 32 rows per bucket
#define NBMAX 3200     // >= ceil(100000/32) = 3125
#define NBP 3200       // padded hist_g row stride (ints)
#define NBLK 128       // hist/scatter chunks
#define SCT 1024       // hist/scatter threads per block
#define CAP 1024       // LDS edge capacity per sort chunk

// ---------------- GEMM1: h = prelu(AX @ Wr^T + br) [f16 out] ----------------
__global__ __launch_bounds__(256, 2)
void gemm128_prelu(const float* __restrict__ X, const float* __restrict__ W,
                   const float* __restrict__ bias, const float* __restrict__ alpha_p,
                   _Float16* __restrict__ out, int N)
{
    __shared__ _Float16 Xs[128 * LDK];
    __shared__ _Float16 Ws[128 * LDK];
    const int tid = threadIdx.x;
    const int bm  = blockIdx.x * 128;
    const float alpha = *alpha_p;

#pragma unroll
    for (int i = 0; i < 16; ++i) {
        int c   = tid + i * 256;
        int row = c >> 5;
        int coff = (c & 31) * 4;
        float4 f = *(const float4*)(W + row * 128 + coff);
        half4 hv = { (_Float16)f.x, (_Float16)f.y, (_Float16)f.z, (_Float16)f.w };
        *(half4*)(&Ws[row * LDK + coff]) = hv;
    }
#pragma unroll
    for (int i = 0; i < 16; ++i) {
        int c   = tid + i * 256;
        int row = c >> 5;
        int coff = (c & 31) * 4;
        int grow = bm + row;
        half4 hv = {};
        if (grow < N) {
            float4 f = *(const float4*)(X + (size_t)grow * 128 + coff);
            hv[0] = (_Float16)f.x; hv[1] = (_Float16)f.y;
            hv[2] = (_Float16)f.z; hv[3] = (_Float16)f.w;
        }
        *(half4*)(&Xs[row * LDK + coff]) = hv;
    }
    __syncthreads();

    const int wave = tid >> 6;
    const int lane = tid & 63;
    const int l15  = lane & 15;
    const int quad = lane >> 4;

    floatx4 acc[2][8] = {};
#pragma unroll
    for (int k0 = 0; k0 < 128; k0 += 32) {
        half8 a0 = *(const half8*)(&Xs[(wave * 32 +      l15) * LDK + k0 + quad * 8]);
        half8 a1 = *(const half8*)(&Xs[(wave * 32 + 16 + l15) * LDK + k0 + quad * 8]);
        half8 b[8];
#pragma unroll
        for (int n = 0; n < 8; ++n)
            b[n] = *(const half8*)(&Ws[(n * 16 + l15) * LDK + k0 + quad * 8]);
#pragma unroll
        for (int n = 0; n < 8; ++n) {
            acc[0][n] = __builtin_amdgcn_mfma_f32_16x16x32_f16(a0, b[n], acc[0][n], 0, 0, 0);
            acc[1][n] = __builtin_amdgcn_mfma_f32_16x16x32_f16(a1, b[n], acc[1][n], 0, 0, 0);
        }
    }

#pragma unroll
    for (int mt = 0; mt < 2; ++mt) {
#pragma unroll
        for (int n = 0; n < 8; ++n) {
#pragma unroll
            for (int r = 0; r < 4; ++r) {
                int row = bm + wave * 32 + mt * 16 + quad * 4 + r;
                int col = n * 16 + l15;
                if (row < N) {
                    float v = acc[mt][n][r] + bias[col];
                    v = (v >= 0.f) ? v : alpha * v;
                    out[(size_t)row * 128 + col] = (_Float16)v;
                }
            }
        }
    }
}

// ---------------- bucket radix pass ----------------
// hist_g[blk*NBP + b] = #edges of bucket b in chunk blk  (contiguous write-out)
__global__ __launch_bounds__(SCT)
void bucket_hist(const int* __restrict__ rows, int* __restrict__ hist_g,
                 int E, int chunk, int NB)
{
    __shared__ int lh[NBMAX];
    int tid = threadIdx.x, blk = blockIdx.x;
    for (int i = tid; i < NB; i += SCT) lh[i] = 0;
    __syncthreads();
    int s = blk * chunk, e = min(E, s + chunk);
    for (int i = s + tid; i < e; i += SCT)
        atomicAdd(&lh[rows[i] >> SHIFT], 1);
    __syncthreads();
    for (int b = tid; b < NB; b += SCT)
        hist_g[blk * NBP + b] = lh[b];
}

// per-bucket serial scan over the NBLK chunk-counts (in place, exclusive)
// thread t owns bucket b; reads/writes coalesced across threads at each blk.
__global__ __launch_bounds__(256)
void bucket_scan1(int* __restrict__ hist_g, int* __restrict__ tot, int NB)
{
    int b = blockIdx.x * 256 + threadIdx.x;
    if (b >= NB) return;
    int run = 0;
#pragma unroll 4
    for (int blk = 0; blk < NBLK; ++blk) {
        int v = hist_g[blk * NBP + b];
        hist_g[blk * NBP + b] = run;
        run += v;
    }
    tot[b] = run;
}

// exclusive scan of bucket totals -> bkt_ptr[0..NB]; ALSO converts W to f16.
__global__ __launch_bounds__(1024)
void bucket_scan2(const int* __restrict__ tot, int* __restrict__ bkt_ptr, int NB, int E,
                  const float* __restrict__ W, _Float16* __restrict__ W16)
{
    __shared__ int sd[1024];
    int t = threadIdx.x;
#pragma unroll
    for (int j = 0; j < 16; ++j) W16[t + j * 1024] = (_Float16)W[t + j * 1024];

    int v[4]; int s = 0;
#pragma unroll
    for (int j = 0; j < 4; ++j) {
        int idx = t * 4 + j;
        v[j] = (idx < NB) ? tot[idx] : 0;
        s += v[j];
    }
    sd[t] = s;
    __syncthreads();
    for (int off = 1; off < 1024; off <<= 1) {
        int x = (t >= off) ? sd[t - off] : 0;
        __syncthreads();
        sd[t] += x;
        __syncthreads();
    }
    int base = (t == 0) ? 0 : sd[t - 1];
#pragma unroll
    for (int j = 0; j < 4; ++j) {
        int idx = t * 4 + j;
        if (idx < NB) { bkt_ptr[idx] = base; base += v[j]; }
    }
    if (t == 0) bkt_ptr[NB] = E;
}

// scatter edges into bucket-contiguous storage; packed (col | rloc<<20, valbits)
__global__ __launch_bounds__(SCT)
void bucket_scatter(const int* __restrict__ rows, const int* __restrict__ cols,
                    const float* __restrict__ vals, const int* __restrict__ bkt_ptr,
                    const int* __restrict__ hist_g, uint2* __restrict__ edges,
                    int E, int chunk, int NB)
{
    __shared__ int cur[NBMAX];
    int tid = threadIdx.x, blk = blockIdx.x;
    for (int b = tid; b < NB; b += SCT)
        cur[b] = bkt_ptr[b] + hist_g[blk * NBP + b];   // contiguous read
    __syncthreads();
    int s = blk * chunk, e = min(E, s + chunk);
    for (int i = s + tid; i < e; i += SCT) {
        int r = rows[i];
        int b = r >> SHIFT;
        uint2 ed;
        ed.x = (unsigned)cols[i] | ((unsigned)(r & 31) << 20);
        ed.y = __float_as_uint(vals[i]);
        int p = atomicAdd(&cur[b], 1);
        edges[p] = ed;
    }
}

// ------- SpMM + GEMM2 fused: per-bucket sort, register accum, MFMA epilogue -
// block = 256 thr = 4 waves; bucket = 32 rows; wave w accumulates rows
// [w*8, w*8+8), lane l = true cols {2l, 2l+1}. Then temp tile -> LDS
// (ALIASED over the dead edge buffers) -> out = prelu(T @ W16^T + b), fp32.
__global__ __launch_bounds__(256)
void spmm_fused(const int* __restrict__ bkt_ptr, const uint2* __restrict__ edges,
                const _Float16* __restrict__ h, const _Float16* __restrict__ W16,
                const float* __restrict__ bias, const float* __restrict__ alpha_p,
                float* __restrict__ out, int N)
{
    __shared__ uint2 ebuf[2 * CAP];          // 16 KB: eL = ebuf, eS = ebuf+CAP
    __shared__ int bins[32], startS[33];
    uint2* eL = ebuf;
    uint2* eS = ebuf + CAP;
    _Float16* T = (_Float16*)ebuf;           // 8.7 KB alias, used after edge loop

    const int tid  = threadIdx.x;
    const int wave = tid >> 6;
    const int lane = tid & 63;
    const int b    = blockIdx.x;
    const int s0   = bkt_ptr[b], e0 = bkt_ptr[b + 1];

    float acc[8][2] = {};

    for (int base = s0; base < e0; base += CAP) {
        const int n = min(CAP, e0 - base);
        if (tid < 32) bins[tid] = 0;
        __syncthreads();
        for (int i = tid; i < n; i += 256) {
            uint2 ed = edges[base + i];
            eL[i] = ed;
            atomicAdd(&bins[ed.x >> 20], 1);
        }
        __syncthreads();
        if (tid < 32) {                       // wave-parallel 32-bin scan
            int x = bins[tid];
#pragma unroll
            for (int off = 1; off < 32; off <<= 1) {
                int y = __shfl_up(x, off);
                if (tid >= off) x += y;
            }
            startS[tid + 1] = x;
            if (tid == 0) startS[0] = 0;
            bins[tid] = x - bins[tid];        // running cursor (exclusive)
        }
        __syncthreads();
        for (int i = tid; i < n; i += 256) {
            uint2 ed = eL[i];
            int p = atomicAdd(&bins[ed.x >> 20], 1);
            eS[p] = ed;
        }
        __syncthreads();

#pragma unroll
        for (int j = 0; j < 8; ++j) {
            int r  = wave * 8 + j;
            int rs = startS[r], re = startS[r + 1];
            float a0r = acc[j][0], a1r = acc[j][1];
            int i = rs;
            for (; i + 7 < re; i += 8) {      // 8 gathers in flight
                uint2 q0 = eS[i],     q1 = eS[i + 1], q2 = eS[i + 2], q3 = eS[i + 3];
                uint2 q4 = eS[i + 4], q5 = eS[i + 5], q6 = eS[i + 6], q7 = eS[i + 7];
                half2v v0 = *(const half2v*)(h + (size_t)(q0.x & 0xFFFFF) * 128 + lane * 2);
                half2v v1 = *(const half2v*)(h + (size_t)(q1.x & 0xFFFFF) * 128 + lane * 2);
                half2v v2 = *(const half2v*)(h + (size_t)(q2.x & 0xFFFFF) * 128 + lane * 2);
                half2v v3 = *(const half2v*)(h + (size_t)(q3.x & 0xFFFFF) * 128 + lane * 2);
                half2v v4 = *(const half2v*)(h + (size_t)(q4.x & 0xFFFFF) * 128 + lane * 2);
                half2v v5 = *(const half2v*)(h + (size_t)(q5.x & 0xFFFFF) * 128 + lane * 2);
                half2v v6 = *(const half2v*)(h + (size_t)(q6.x & 0xFFFFF) * 128 + lane * 2);
                half2v v7 = *(const half2v*)(h + (size_t)(q7.x & 0xFFFFF) * 128 + lane * 2);
                float w0 = __uint_as_float(q0.y), w1 = __uint_as_float(q1.y);
                float w2 = __uint_as_float(q2.y), w3 = __uint_as_float(q3.y);
                float w4 = __uint_as_float(q4.y), w5 = __uint_as_float(q5.y);
                float w6 = __uint_as_float(q6.y), w7 = __uint_as_float(q7.y);
                a0r += w0 * (float)v0[0]; a1r += w0 * (float)v0[1];
                a0r += w1 * (float)v1[0]; a1r += w1 * (float)v1[1];
                a0r += w2 * (float)v2[0]; a1r += w2 * (float)v2[1];
                a0r += w3 * (float)v3[0]; a1r += w3 * (float)v3[1];
                a0r += w4 * (float)v4[0]; a1r += w4 * (float)v4[1];
                a0r += w5 * (float)v5[0]; a1r += w5 * (float)v5[1];
                a0r += w6 * (float)v6[0]; a1r += w6 * (float)v6[1];
                a0r += w7 * (float)v7[0]; a1r += w7 * (float)v7[1];
            }
            for (; i + 1 < re; i += 2) {
                uint2 q0 = eS[i], q1 = eS[i + 1];
                half2v v0 = *(const half2v*)(h + (size_t)(q0.x & 0xFFFFF) * 128 + lane * 2);
                half2v v1 = *(const half2v*)(h + (size_t)(q1.x & 0xFFFFF) * 128 + lane * 2);
                float w0 = __uint_as_float(q0.y), w1 = __uint_as_float(q1.y);
                a0r += w0 * (float)v0[0]; a1r += w0 * (float)v0[1];
                a0r += w1 * (float)v1[0]; a1r += w1 * (float)v1[1];
            }
            if (i < re) {
                uint2 q0 = eS[i];
                half2v v0 = *(const half2v*)(h + (size_t)(q0.x & 0xFFFFF) * 128 + lane * 2);
                float w0 = __uint_as_float(q0.y);
                a0r += w0 * (float)v0[0]; a1r += w0 * (float)v0[1];
            }
            acc[j][0] = a0r; acc[j][1] = a1r;
        }
        __syncthreads();   // all waves done with eL/eS this chunk
    }

    // T aliases ebuf — safe: loop's final barrier ordered all eS reads before this
#pragma unroll
    for (int j = 0; j < 8; ++j) {
        half2v o = { (_Float16)acc[j][0], (_Float16)acc[j][1] };
        *(half2v*)(&T[(wave * 8 + j) * LDK + lane * 2]) = o;
    }
    __syncthreads();

    // GEMM2 epilogue: out[32x128] = prelu(T @ W16^T + bias)
    const float alpha = *alpha_p;
    const int l15  = lane & 15;
    const int quad = lane >> 4;
    floatx4 c[2][2] = {};
#pragma unroll
    for (int k0 = 0; k0 < 128; k0 += 32) {
        half8 a0 = *(const half8*)(&T[(     l15) * LDK + k0 + quad * 8]);
        half8 a1 = *(const half8*)(&T[(16 + l15) * LDK + k0 + quad * 8]);
#pragma unroll
        for (int nt = 0; nt < 2; ++nt) {
            int nrow = (wave * 2 + nt) * 16 + l15;
            half8 bf = *(const half8*)(W16 + nrow * 128 + k0 + quad * 8);
            c[0][nt] = __builtin_amdgcn_mfma_f32_16x16x32_f16(a0, bf, c[0][nt], 0, 0, 0);
            c[1][nt] = __builtin_amdgcn_mfma_f32_16x16x32_f16(a1, bf, c[1][nt], 0, 0, 0);
        }
    }
    const int row0 = b << SHIFT;
#pragma unroll
    for (int mt = 0; mt < 2; ++mt) {
#pragma unroll
        for (int nt = 0; nt < 2; ++nt) {
            int col = (wave * 2 + nt) * 16 + l15;
            float bcol = bias[col];
#pragma unroll
            for (int r = 0; r < 4; ++r) {
                int row = row0 + mt * 16 + quad * 4 + r;
                if (row < N) {
                    float v = c[mt][nt][r] + bcol;
                    v = (v >= 0.f) ? v : alpha * v;
                    out[(size_t)row * 128 + col] = v;
                }
            }
        }
    }
}

// ---------------- launcher ----------------
static inline size_t align256(size_t x) { return (x + 255) & ~(size_t)255; }

extern "C" void kernel_launch(void* const* d_in, const int* in_sizes, int n_in,
                              void* d_out, int out_size, void* d_ws, size_t ws_size,
                              hipStream_t stream)
{
    const float* AX        = (const float*)d_in[0];
    const int*   A_row     = (const int*)  d_in[1];
    const int*   A_col     = (const int*)  d_in[2];
    const float* A_val     = (const float*)d_in[3];
    const float* Wr_w      = (const float*)d_in[4];
    const float* Wr_b      = (const float*)d_in[5];
    const float* W_w       = (const float*)d_in[6];
    const float* W_b       = (const float*)d_in[7];
    const float* g_alpha   = (const float*)d_in[8];
    const float* act_alpha = (const float*)d_in[9];

    const int N = in_sizes[0] / 128;
    const int E = in_sizes[1];
    const int NB = (N + 31) >> SHIFT;            // 3125
    const int chunk = (E + NBLK - 1) / NBLK;     // 12500

    char* ws = (char*)d_ws;
    size_t off = 0;
    _Float16* h      = (_Float16*)(ws + off); off += align256((size_t)N * 128 * 2);
    uint2*    edges  = (uint2*)   (ws + off); off += align256((size_t)E * 8);
    int*      hist_g = (int*)     (ws + off); off += align256((size_t)NBLK * NBP * 4);
    int*      tot    = (int*)     (ws + off); off += align256((size_t)NB * 4);
    int*      bkt_ptr= (int*)     (ws + off); off += align256((size_t)(NB + 1) * 4);
    _Float16* W16    = (_Float16*)(ws + off); off += align256((size_t)128 * 128 * 2);
    (void)ws_size; (void)n_in; (void)out_size;

    const int gemm_grid = (N + 127) / 128;

    gemm128_prelu<<<gemm_grid, 256, 0, stream>>>(AX, Wr_w, Wr_b, g_alpha, h, N);

    bucket_hist<<<NBLK, SCT, 0, stream>>>(A_row, hist_g, E, chunk, NB);
    bucket_scan1<<<(NB + 255) / 256, 256, 0, stream>>>(hist_g, tot, NB);
    bucket_scan2<<<1, 1024, 0, stream>>>(tot, bkt_ptr, NB, E, W_w, W16);
    bucket_scatter<<<NBLK, SCT, 0, stream>>>(A_row, A_col, A_val, bkt_ptr, hist_g, edges, E, chunk, NB);

    spmm_fused<<<NB, 256, 0, stream>>>(bkt_ptr, edges, h, W16, W_b, act_alpha,
                                       (float*)d_out, N);
}